// Round 2
// baseline (152.544 us; speedup 1.0000x reference)
//
#include <hip/hip_runtime.h>

#define T_STEPS 20
#define NI 5
#define NH 100
#define NO 3

// One thread per batch element. h OUTER (unrolled x2), t INNER fully unrolled.
// acc[20][3] spike-train accumulators live in arch VGPRs.
//
// __launch_bounds__(256, 2): min 2 waves/EU -> VGPR cap 256. Without this the
// backend's occupancy-greedy heuristic capped arch VGPRs at 36 and parked the
// 60 accumulators in AGPRs, paying v_accvgpr_read/write around every acc FMA
// (+6 VALU per (h,t), measured ~14 vs theoretical 8 inst/iter). Grid supplies
// only 4 waves/SIMD, so high occupancy bought nothing.
//
// Rounding discipline (unchanged from passing R1 kernel): recurrences use
// __fmul_rn/__fadd_rn/__fsub_rn (no FMA contraction) to match numpy's
// separate-op rounding; threshold crossings are the only failure mode.
// Dot products use FMA. Per-accumulator update order stays h-ascending.
__global__ __launch_bounds__(256, 2) void snn_kernel(
    const float* __restrict__ x,
    const float* __restrict__ W1,
    const float* __restrict__ b1,
    const float* __restrict__ W2,
    const float* __restrict__ b2,
    float* __restrict__ out, int B)
{
    int b = blockIdx.x * blockDim.x + threadIdx.x;
    if (b >= B) return;

    float xv[NI];
#pragma unroll
    for (int i = 0; i < NI; ++i) xv[i] = x[b * NI + i];

    float acc[T_STEPS][NO];
#pragma unroll
    for (int t = 0; t < T_STEPS; ++t)
#pragma unroll
        for (int o = 0; o < NO; ++o) acc[t][o] = 0.0f;

#pragma unroll 1
    for (int h = 0; h < NH; h += 2) {
        // Two independent hidden units per iteration: ILP across the two
        // dependent membrane chains; adjacent W1 rows merge into wide s_loads.
        float cA = b1[h];
        float cB = b1[h + 1];
#pragma unroll
        for (int i = 0; i < NI; ++i) {
            cA = __builtin_fmaf(xv[i], W1[h * NI + i], cA);
            cB = __builtin_fmaf(xv[i], W1[(h + 1) * NI + i], cB);
        }

        float wA0 = W2[0 * NH + h], wB0 = W2[0 * NH + h + 1];
        float wA1 = W2[1 * NH + h], wB1 = W2[1 * NH + h + 1];
        float wA2 = W2[2 * NH + h], wB2 = W2[2 * NH + h + 1];

        float memA = 0.0f, memB = 0.0f;
        bool spA = false, spB = false;  // reset cond == previous spike cond
#pragma unroll
        for (int t = 0; t < T_STEPS; ++t) {
            float tA = __fmul_rn(0.95f, memA);
            float tB = __fmul_rn(0.95f, memB);
            tA = __fadd_rn(tA, cA);
            tB = __fadd_rn(tB, cB);
            memA = __fsub_rn(tA, spA ? 1.0f : 0.0f);
            memB = __fsub_rn(tB, spB ? 1.0f : 0.0f);
            spA = memA > 1.0f;           // == (memA - 1 > 0) exactly in fp32
            spB = memB > 1.0f;
            float fA = spA ? 1.0f : 0.0f;
            float fB = spB ? 1.0f : 0.0f;
            // Order per accumulator: h (A) then h+1 (B) — identical to the
            // sequential-h version that passed with absmax 0.
            acc[t][0] = __builtin_fmaf(fA, wA0, acc[t][0]);
            acc[t][0] = __builtin_fmaf(fB, wB0, acc[t][0]);
            acc[t][1] = __builtin_fmaf(fA, wA1, acc[t][1]);
            acc[t][1] = __builtin_fmaf(fB, wB1, acc[t][1]);
            acc[t][2] = __builtin_fmaf(fA, wA2, acc[t][2]);
            acc[t][2] = __builtin_fmaf(fB, wB2, acc[t][2]);
        }
    }

    // Layer-2 LIF dynamics + spike count
    float m2[NO] = {0.0f, 0.0f, 0.0f};
    float cnt[NO] = {0.0f, 0.0f, 0.0f};
    bool r2[NO] = {false, false, false};
#pragma unroll
    for (int t = 0; t < T_STEPS; ++t) {
#pragma unroll
        for (int o = 0; o < NO; ++o) {
            float cur = __fadd_rn(acc[t][o], b2[o]);   // (sum) + b2, ref order
            float tmp = __fmul_rn(0.95f, m2[o]);
            tmp = __fadd_rn(tmp, cur);
            m2[o] = __fsub_rn(tmp, r2[o] ? 1.0f : 0.0f);
            r2[o] = m2[o] > 1.0f;
            cnt[o] = __fadd_rn(cnt[o], r2[o] ? 1.0f : 0.0f);
        }
    }
#pragma unroll
    for (int o = 0; o < NO; ++o) out[b * NO + o] = cnt[o];
}

extern "C" void kernel_launch(void* const* d_in, const int* in_sizes, int n_in,
                              void* d_out, int out_size, void* d_ws, size_t ws_size,
                              hipStream_t stream) {
    const float* x  = (const float*)d_in[0];
    const float* W1 = (const float*)d_in[1];
    const float* b1 = (const float*)d_in[2];
    const float* W2 = (const float*)d_in[3];
    const float* b2 = (const float*)d_in[4];
    float* out = (float*)d_out;

    int B = in_sizes[0] / NI;  // 262144
    int threads = 256;
    int blocks = (B + threads - 1) / threads;
    snn_kernel<<<blocks, threads, 0, stream>>>(x, W1, b1, W2, b2, out, B);
}